// Round 1
// baseline (235.458 us; speedup 1.0000x reference)
//
#include <hip/hip_runtime.h>
#include <hip/hip_bf16.h>
#include <math.h>

// Problem constants
#define B_  1024
#define N_  32
#define D_  512
#define H_  1024   // 2*D
#define EPS_ 1e-5f

typedef __attribute__((ext_vector_type(8))) short bf16x8;   // 8 bf16 = 4 VGPRs
typedef __attribute__((ext_vector_type(4))) float f32x4;
using bf16 = __hip_bfloat16;

// ---------------------------------------------------------------------------
// Transpose + cast: in [mat][R][C] f32  ->  out [mat][C][R] bf16
// grid: (C/32, R/32, nmat), block 256
// ---------------------------------------------------------------------------
__global__ __launch_bounds__(256) void transpose_cast_kernel(
    const float* __restrict__ in, bf16* __restrict__ out, int R, int C) {
  __shared__ float tile[32][33];
  const size_t mat = (size_t)blockIdx.z * (size_t)R * (size_t)C;
  const float* inp = in + mat;
  bf16* outp = out + mat;
  const int c0 = blockIdx.x * 32, r0 = blockIdx.y * 32;
  const int tx = threadIdx.x & 31, ty = threadIdx.x >> 5;   // 32 x 8
#pragma unroll
  for (int i = 0; i < 4; ++i) {
    int r = ty + i * 8;
    tile[r][tx] = inp[(size_t)(r0 + r) * C + (c0 + tx)];
  }
  __syncthreads();
#pragma unroll
  for (int i = 0; i < 4; ++i) {
    int r = ty + i * 8;   // row of output tile = column of input tile
    outp[(size_t)(c0 + r) * R + (r0 + tx)] = __float2bfloat16(tile[tx][r]);
  }
}

// ---------------------------------------------------------------------------
// Kernel A: x_pre[b,n,d] = sum_k A[p[k], n] * z[b,k,d]; x = LN(x_pre)*g+b
// writes x bf16 in [m][b][d] layout; also writes inverse permutation.
// grid: B_ blocks, 256 threads. Each thread: all 32 n-rows at cols {t, t+256}.
// ---------------------------------------------------------------------------
__global__ __launch_bounds__(256) void mix_ln_kernel(
    const float* __restrict__ z, const int* __restrict__ idx,
    const float* __restrict__ A, const float* __restrict__ gamma,
    const float* __restrict__ beta, bf16* __restrict__ x_ws,
    int* __restrict__ inv_ws) {
  __shared__ float As[32][32];      // As[k][n] = A[p[k]][n]
  __shared__ int   p[32];
  __shared__ float red1[4][32];
  __shared__ float red2[4][32];
  __shared__ float meanS[32];
  __shared__ float rstdS[32];

  const int b = blockIdx.x;
  const int t = threadIdx.x;
  const int lane = t & 63, wid = t >> 6;

  if (t < 32) {
    int v = idx[b * 32 + t];
    p[t] = v;
    inv_ws[b * 32 + v] = t;   // inv[b][v] = position of value v in idx[b]
  }
  __syncthreads();
  for (int i = t; i < 1024; i += 256) {
    int k = i >> 5, n = i & 31;
    As[k][n] = A[p[k] * 32 + n];
  }
  __syncthreads();

  const int d0 = t, d1 = t + 256;
  const float* zb = z + (size_t)b * (N_ * D_);
  float acc0[32], acc1[32];
#pragma unroll
  for (int n = 0; n < 32; ++n) { acc0[n] = 0.f; acc1[n] = 0.f; }

  for (int k = 0; k < 32; ++k) {
    float z0 = zb[k * D_ + d0];
    float z1 = zb[k * D_ + d1];
#pragma unroll
    for (int c = 0; c < 8; ++c) {
      float4 a4 = *(const float4*)&As[k][c * 4];
      acc0[c * 4 + 0] = fmaf(a4.x, z0, acc0[c * 4 + 0]);
      acc1[c * 4 + 0] = fmaf(a4.x, z1, acc1[c * 4 + 0]);
      acc0[c * 4 + 1] = fmaf(a4.y, z0, acc0[c * 4 + 1]);
      acc1[c * 4 + 1] = fmaf(a4.y, z1, acc1[c * 4 + 1]);
      acc0[c * 4 + 2] = fmaf(a4.z, z0, acc0[c * 4 + 2]);
      acc1[c * 4 + 2] = fmaf(a4.z, z1, acc1[c * 4 + 2]);
      acc0[c * 4 + 3] = fmaf(a4.w, z0, acc0[c * 4 + 3]);
      acc1[c * 4 + 3] = fmaf(a4.w, z1, acc1[c * 4 + 3]);
    }
  }

  // Per-row mean / var across the 512 columns (2 per thread).
#pragma unroll
  for (int n = 0; n < 32; ++n) {
    float v1 = acc0[n] + acc1[n];
    float v2 = acc0[n] * acc0[n] + acc1[n] * acc1[n];
#pragma unroll
    for (int mk = 1; mk < 64; mk <<= 1) {
      v1 += __shfl_xor(v1, mk);
      v2 += __shfl_xor(v2, mk);
    }
    if (lane == 0) { red1[wid][n] = v1; red2[wid][n] = v2; }
  }
  __syncthreads();
  if (t < 32) {
    float S1 = red1[0][t] + red1[1][t] + red1[2][t] + red1[3][t];
    float S2 = red2[0][t] + red2[1][t] + red2[2][t] + red2[3][t];
    float mean = S1 * (1.f / D_);
    float var  = S2 * (1.f / D_) - mean * mean;
    meanS[t] = mean;
    rstdS[t] = rsqrtf(var + EPS_);
  }
  __syncthreads();

  const float g0 = gamma[d0], g1 = gamma[d1];
  const float be0 = beta[d0], be1 = beta[d1];
#pragma unroll
  for (int n = 0; n < 32; ++n) {
    float mn = meanS[n], rs = rstdS[n];
    float x0 = (acc0[n] - mn) * rs * g0 + be0;
    float x1 = (acc1[n] - mn) * rs * g1 + be1;
    size_t base = ((size_t)n * B_ + b) * D_;
    x_ws[base + d0] = __float2bfloat16(x0);
    x_ws[base + d1] = __float2bfloat16(x1);
  }
}

// ---------------------------------------------------------------------------
// GEMM1: per m: H[m] = elu( X[m](1024x512) @ W1t[m]^T + b1[m] ), bf16 out.
// A,B both stored as [rows][K] bf16 (B^T layout). 128x128 tile, BK=32,
// 4 waves 2x2, each wave 64x64 via 4x4 frags of mfma_f32_16x16x32_bf16.
// grid (8, 8, 32), block 256.
// ---------------------------------------------------------------------------
__global__ __launch_bounds__(256) void gemm1_kernel(
    const bf16* __restrict__ X,    // [32][1024][512]
    const bf16* __restrict__ W1t,  // [32][1024][512]
    const float* __restrict__ b1,  // [32][1024]
    bf16* __restrict__ Hout) {     // [32][1024][1024]
  constexpr int Md = 1024, Nd = 1024, Kd = 512;
  __shared__ short Asb[128 * 32];
  __shared__ short Bsb[128 * 32];

  const int m = blockIdx.z;
  const int t = threadIdx.x;
  const int lane = t & 63, wid = t >> 6;
  const int wr = wid >> 1, wc = wid & 1;
  const int llo = lane & 15, lhi = lane >> 4;
  const int row0 = blockIdx.x * 128, col0 = blockIdx.y * 128;

  const bf16* Ag = X + (size_t)m * Md * Kd + (size_t)row0 * Kd;
  const bf16* Bg = W1t + (size_t)m * Nd * Kd + (size_t)col0 * Kd;

  const int c0 = t, c1 = t + 256;             // 16B chunk ids (512 per tile)
  const int ar0 = c0 >> 2, ak0 = (c0 & 3) << 3;
  const int ar1 = c1 >> 2, ak1 = (c1 & 3) << 3;

  const f32x4 fzero = {0.f, 0.f, 0.f, 0.f};
  f32x4 acc[4][4];
#pragma unroll
  for (int i = 0; i < 4; ++i)
#pragma unroll
    for (int j = 0; j < 4; ++j) acc[i][j] = fzero;

  for (int ks = 0; ks < Kd / 32; ++ks) {
    const int kb = ks * 32;
    int4 a0 = *(const int4*)(Ag + (size_t)ar0 * Kd + kb + ak0);
    int4 a1 = *(const int4*)(Ag + (size_t)ar1 * Kd + kb + ak1);
    int4 b0 = *(const int4*)(Bg + (size_t)ar0 * Kd + kb + ak0);
    int4 b1r = *(const int4*)(Bg + (size_t)ar1 * Kd + kb + ak1);
    __syncthreads();
    *(int4*)&Asb[c0 * 8] = a0;
    *(int4*)&Asb[c1 * 8] = a1;
    *(int4*)&Bsb[c0 * 8] = b0;
    *(int4*)&Bsb[c1 * 8] = b1r;
    __syncthreads();
    bf16x8 av[4], bv[4];
#pragma unroll
    for (int i = 0; i < 4; ++i)
      av[i] = *(const bf16x8*)&Asb[(wr * 64 + i * 16 + llo) * 32 + lhi * 8];
#pragma unroll
    for (int j = 0; j < 4; ++j)
      bv[j] = *(const bf16x8*)&Bsb[(wc * 64 + j * 16 + llo) * 32 + lhi * 8];
#pragma unroll
    for (int i = 0; i < 4; ++i)
#pragma unroll
      for (int j = 0; j < 4; ++j)
        acc[i][j] = __builtin_amdgcn_mfma_f32_16x16x32_bf16(av[i], bv[j], acc[i][j], 0, 0, 0);
  }

  bf16* Hm = Hout + (size_t)m * Md * Nd;
#pragma unroll
  for (int j = 0; j < 4; ++j) {
    const int col = col0 + wc * 64 + j * 16 + llo;
    const float bias = b1[m * Nd + col];
#pragma unroll
    for (int i = 0; i < 4; ++i) {
      const int rowb = row0 + wr * 64 + i * 16 + lhi * 4;
#pragma unroll
      for (int r = 0; r < 4; ++r) {
        float v = acc[i][j][r] + bias;
        v = v > 0.f ? v : expm1f(v);    // ELU (alpha=1)
        Hm[(size_t)(rowb + r) * Nd + col] = __float2bfloat16(v);
      }
    }
  }
}

// ---------------------------------------------------------------------------
// GEMM2: per m: Y = H[m](1024x1024) @ W2t[m]^T + b2[m]; out[b, inv[b][m], :]
//        = Y[b,:] + x[m][b,:].   grid (8, 4, 32), block 256.
// ---------------------------------------------------------------------------
__global__ __launch_bounds__(256) void gemm2_kernel(
    const bf16* __restrict__ Hin,  // [32][1024][1024]
    const bf16* __restrict__ W2t,  // [32][512][1024]
    const float* __restrict__ b2,  // [32][512]
    const bf16* __restrict__ Xb,   // [32][1024][512]
    const int* __restrict__ inv,   // [1024][32]
    float* __restrict__ out) {     // [1024][32][512]
  constexpr int Md = 1024, Nd = 512, Kd = 1024;
  __shared__ short Asb[128 * 32];
  __shared__ short Bsb[128 * 32];

  const int m = blockIdx.z;
  const int t = threadIdx.x;
  const int lane = t & 63, wid = t >> 6;
  const int wr = wid >> 1, wc = wid & 1;
  const int llo = lane & 15, lhi = lane >> 4;
  const int row0 = blockIdx.x * 128, col0 = blockIdx.y * 128;

  const bf16* Ag = Hin + (size_t)m * Md * Kd + (size_t)row0 * Kd;
  const bf16* Bg = W2t + (size_t)m * Nd * Kd + (size_t)col0 * Kd;

  const int c0 = t, c1 = t + 256;
  const int ar0 = c0 >> 2, ak0 = (c0 & 3) << 3;
  const int ar1 = c1 >> 2, ak1 = (c1 & 3) << 3;

  const f32x4 fzero = {0.f, 0.f, 0.f, 0.f};
  f32x4 acc[4][4];
#pragma unroll
  for (int i = 0; i < 4; ++i)
#pragma unroll
    for (int j = 0; j < 4; ++j) acc[i][j] = fzero;

  for (int ks = 0; ks < Kd / 32; ++ks) {
    const int kb = ks * 32;
    int4 a0 = *(const int4*)(Ag + (size_t)ar0 * Kd + kb + ak0);
    int4 a1 = *(const int4*)(Ag + (size_t)ar1 * Kd + kb + ak1);
    int4 b0 = *(const int4*)(Bg + (size_t)ar0 * Kd + kb + ak0);
    int4 b1r = *(const int4*)(Bg + (size_t)ar1 * Kd + kb + ak1);
    __syncthreads();
    *(int4*)&Asb[c0 * 8] = a0;
    *(int4*)&Asb[c1 * 8] = a1;
    *(int4*)&Bsb[c0 * 8] = b0;
    *(int4*)&Bsb[c1 * 8] = b1r;
    __syncthreads();
    bf16x8 av[4], bv[4];
#pragma unroll
    for (int i = 0; i < 4; ++i)
      av[i] = *(const bf16x8*)&Asb[(wr * 64 + i * 16 + llo) * 32 + lhi * 8];
#pragma unroll
    for (int j = 0; j < 4; ++j)
      bv[j] = *(const bf16x8*)&Bsb[(wc * 64 + j * 16 + llo) * 32 + lhi * 8];
#pragma unroll
    for (int i = 0; i < 4; ++i)
#pragma unroll
      for (int j = 0; j < 4; ++j)
        acc[i][j] = __builtin_amdgcn_mfma_f32_16x16x32_bf16(av[i], bv[j], acc[i][j], 0, 0, 0);
  }

  const bf16* Xm = Xb + (size_t)m * (size_t)Md * 512;
  float bias[4];
#pragma unroll
  for (int j = 0; j < 4; ++j)
    bias[j] = b2[m * Nd + col0 + wc * 64 + j * 16 + llo];

#pragma unroll
  for (int i = 0; i < 4; ++i) {
    const int rowb = row0 + wr * 64 + i * 16 + lhi * 4;
#pragma unroll
    for (int r = 0; r < 4; ++r) {
      const int b_ = rowb + r;
      const int n_out = inv[b_ * 32 + m];
      float* orow = out + ((size_t)b_ * 32 + n_out) * 512;
      const bf16* xrow = Xm + (size_t)b_ * 512;
#pragma unroll
      for (int j = 0; j < 4; ++j) {
        const int col = col0 + wc * 64 + j * 16 + llo;
        float v = acc[i][j][r] + bias[j] + __bfloat162float(xrow[col]);
        orow[col] = v;
      }
    }
  }
}

// ---------------------------------------------------------------------------
extern "C" void kernel_launch(void* const* d_in, const int* in_sizes, int n_in,
                              void* d_out, int out_size, void* d_ws, size_t ws_size,
                              hipStream_t stream) {
  const float* z     = (const float*)d_in[0];
  const int*   idx   = (const int*)d_in[1];
  const float* A     = (const float*)d_in[2];
  const float* W1    = (const float*)d_in[3];
  const float* b1    = (const float*)d_in[4];
  const float* W2    = (const float*)d_in[5];
  const float* b2    = (const float*)d_in[6];
  const float* gamma = (const float*)d_in[7];
  const float* beta  = (const float*)d_in[8];
  float* out = (float*)d_out;
  char* ws = (char*)d_ws;

  // workspace layout (bytes)
  const size_t OFF_X   = 0;           // bf16 [32][1024][512]  : 32 MiB
  const size_t OFF_H   = 33554432;    // bf16 [32][1024][1024] : 64 MiB
  const size_t OFF_W1T = 100663296;   // bf16 [32][1024][512]  : 32 MiB
  const size_t OFF_W2T = 134217728;   // bf16 [32][512][1024]  : 32 MiB
  const size_t OFF_INV = 167772160;   // int  [1024][32]       : 128 KiB
  const size_t NEED    = 167903232;
  if (ws_size < NEED) return;   // insufficient scratch -> bench will flag

  bf16* Xb  = (bf16*)(ws + OFF_X);
  bf16* Hb  = (bf16*)(ws + OFF_H);
  bf16* W1t = (bf16*)(ws + OFF_W1T);
  bf16* W2t = (bf16*)(ws + OFF_W2T);
  int*  inv = (int*)(ws + OFF_INV);

  // W1 [32][512][1024] -> W1t [32][1024][512]
  transpose_cast_kernel<<<dim3(32, 16, 32), 256, 0, stream>>>(W1, W1t, 512, 1024);
  // W2 [32][1024][512] -> W2t [32][512][1024]
  transpose_cast_kernel<<<dim3(16, 32, 32), 256, 0, stream>>>(W2, W2t, 1024, 512);

  mix_ln_kernel<<<dim3(B_), 256, 0, stream>>>(z, idx, A, gamma, beta, Xb, inv);

  gemm1_kernel<<<dim3(8, 8, 32), 256, 0, stream>>>(Xb, W1t, b1, Hb);
  gemm2_kernel<<<dim3(8, 4, 32), 256, 0, stream>>>(Hb, W2t, b2, Xb, inv, out);
}